// Round 10
// baseline (97.916 us; speedup 1.0000x reference)
//
#include <hip/hip_runtime.h>
#include <hip/hip_fp16.h>
#include <hip/hip_bf16.h>
#include <math.h>

// GraphAttention: Q=4, N=50000, K=8, F_IN=128, F_OUT=64
//   y  = query @ W1        (MFMA: A=bf16(query), B=W1 split hi+lo bf16; f16 out)
//   s1 = tanh(mean_k y[e]+b1) . W2
//   score = mean_k s1[e] + b2
//   softmax without max-sub (scores bounded ~|2|): w=exp(s)/Z
//   ctx = (sum_n exp(s_n) * values[n]) / Z
// 5 launches: k_prep (parallel W1 pack -> global, ~1us), k_xw (B from L2-hot
// global, no LDS/sync), k_agg, k_ctx (score+exp+weighted sum fused), k_final.

#define FIN 128
#define FOUT 64
#define KN 8
#define CTXB 250   // context blocks per q -> chunk = exactly 200 nodes

typedef short bf16x8 __attribute__((ext_vector_type(8)));
typedef float f32x4 __attribute__((ext_vector_type(4)));

__device__ inline short f2bf(float x) {           // RNE via HW cvt
    __hip_bfloat16 b = __float2bfloat16(x);
    return *reinterpret_cast<short*>(&b);
}
__device__ inline float bf2f(short s) {
    return __uint_as_float(((unsigned)(unsigned short)s) << 16);
}

// ---------------- Stage 0: pack W1 -> global hi/lo bf16 MFMA B-frags ----------------
// 16 blocks x 64 lanes: block = frag-group g6 (kk*4+nt), lane = MFMA lane.
__global__ __launch_bounds__(64) void k_prep(const float* __restrict__ W1,
                                             short* __restrict__ W1pk) {
    const int g6 = blockIdx.x;
    const int lane = threadIdx.x;
    const int kk = g6 >> 2, nt = g6 & 3;
    const int lg = lane >> 4, lr = lane & 15;
    const int f = nt * 16 + lr;
    const int kbase = kk * 32 + lg * 8;
    bf16x8 hi, lo;
    #pragma unroll
    for (int j = 0; j < 8; ++j) {
        float w = W1[(kbase + j) * FOUT + f];
        short h = f2bf(w);
        hi[j] = h;
        lo[j] = f2bf(w - bf2f(h));
    }
    ((bf16x8*)W1pk)[g6 * 64 + lane] = hi;
    ((bf16x8*)W1pk)[1024 + g6 * 64 + lane] = lo;
}

// ---------------- Stage 1: y = query @ W1 ----------------
// 4 waves/block, 2 tiles (32 nodes)/wave; 16 A-loads hoisted; B-frags from
// L2-hot packed global; A-cvt via HW cvt_pk (compiler-fused).
__global__ __launch_bounds__(256, 3) void k_xw(const float* __restrict__ query,
                                               const short* __restrict__ W1pk,
                                               __half* __restrict__ y, int N) {
    const int tid = threadIdx.x;
    const int wave = tid >> 6, lane = tid & 63;
    const int lg = lane >> 4, lr = lane & 15;
    const int q = blockIdx.y;
    const int base = blockIdx.x * 128 + wave * 32;
    const float* qb = query + (size_t)q * N * FIN;
    __half* yq = y + (size_t)q * N * FOUT;
    const bf16x8* Bp = (const bf16x8*)W1pk;

    int n0 = base + lr;       if (n0 >= N) n0 = N - 1;
    int n1 = base + 16 + lr;  if (n1 >= N) n1 = N - 1;
    const float4* r0 = (const float4*)(qb + (size_t)n0 * FIN);
    const float4* r1 = (const float4*)(qb + (size_t)n1 * FIN);

    float4 a0[8], a1[8];
    #pragma unroll
    for (int kk = 0; kk < 4; ++kk) {
        a0[2 * kk]     = r0[kk * 8 + lg * 2];
        a0[2 * kk + 1] = r0[kk * 8 + lg * 2 + 1];
        a1[2 * kk]     = r1[kk * 8 + lg * 2];
        a1[2 * kk + 1] = r1[kk * 8 + lg * 2 + 1];
    }

    f32x4 acc0[4], acc1[4];
    #pragma unroll
    for (int nt = 0; nt < 4; ++nt) { acc0[nt] = (f32x4)0.f; acc1[nt] = (f32x4)0.f; }

    #pragma unroll
    for (int kk = 0; kk < 4; ++kk) {
        bf16x8 A0, A1;
        const float* x0 = (const float*)&a0[2 * kk];
        const float* x1 = (const float*)&a1[2 * kk];
        #pragma unroll
        for (int j = 0; j < 8; ++j) { A0[j] = f2bf(x0[j]); A1[j] = f2bf(x1[j]); }
        #pragma unroll
        for (int nt = 0; nt < 4; ++nt) {
            bf16x8 Bhi = Bp[(kk * 4 + nt) * 64 + lane];
            bf16x8 Blo = Bp[1024 + (kk * 4 + nt) * 64 + lane];
            acc0[nt] = __builtin_amdgcn_mfma_f32_16x16x32_bf16(A0, Bhi, acc0[nt], 0, 0, 0);
            acc0[nt] = __builtin_amdgcn_mfma_f32_16x16x32_bf16(A0, Blo, acc0[nt], 0, 0, 0);
            acc1[nt] = __builtin_amdgcn_mfma_f32_16x16x32_bf16(A1, Bhi, acc1[nt], 0, 0, 0);
            acc1[nt] = __builtin_amdgcn_mfma_f32_16x16x32_bf16(A1, Blo, acc1[nt], 0, 0, 0);
        }
    }
    #pragma unroll
    for (int r = 0; r < 4; ++r) {
        int m0 = base + lg * 4 + r;
        int m1 = base + 16 + lg * 4 + r;
        if (m0 < N) {
            #pragma unroll
            for (int nt = 0; nt < 4; ++nt)
                yq[(size_t)m0 * FOUT + nt * 16 + lr] = __float2half(acc0[nt][r]);
        }
        if (m1 < N) {
            #pragma unroll
            for (int nt = 0; nt < 4; ++nt)
                yq[(size_t)m1 * FOUT + nt * 16 + lr] = __float2half(acc1[nt][r]);
        }
    }
}

// ---------------- Stage 2: s1 = tanh(mean_k y[e]+b1).W2 ----------------
// 2 nodes/wave, lane = feature-pair; 8 independent coalesced row gathers.
__global__ __launch_bounds__(256) void k_agg(const __half* __restrict__ y,
                                             const int* __restrict__ edges,
                                             const float* __restrict__ b1,
                                             const float* __restrict__ W2,
                                             float* __restrict__ s1, int N) {
    const int tid = threadIdx.x;
    const int wave = tid >> 6, lane = tid & 63;
    const int half = lane >> 5, fl = lane & 31;
    const int q = blockIdx.y;
    const int n = blockIdx.x * 8 + wave * 2 + half;
    const int nc = n < N ? n : N - 1;
    const __half* yq = y + (size_t)q * N * FOUT;

    const int4* erow = (const int4*)(edges + (size_t)nc * KN);
    int4 ea = erow[0], eb = erow[1];

    const __half2* y2 = (const __half2*)yq;
    __half2 v0 = y2[(size_t)ea.x * 32 + fl];
    __half2 v1 = y2[(size_t)ea.y * 32 + fl];
    __half2 v2 = y2[(size_t)ea.z * 32 + fl];
    __half2 v3 = y2[(size_t)ea.w * 32 + fl];
    __half2 v4 = y2[(size_t)eb.x * 32 + fl];
    __half2 v5 = y2[(size_t)eb.y * 32 + fl];
    __half2 v6 = y2[(size_t)eb.z * 32 + fl];
    __half2 v7 = y2[(size_t)eb.w * 32 + fl];

    __half2 s01 = __hadd2(v0, v1), s23 = __hadd2(v2, v3);
    __half2 s45 = __hadd2(v4, v5), s67 = __hadd2(v6, v7);
    __half2 sum = __hadd2(__hadd2(s01, s23), __hadd2(s45, s67));
    float2 sf = __half22float2(sum);

    float2 bv = *(const float2*)(b1 + fl * 2);
    float2 wv = *(const float2*)(W2 + fl * 2);
    float x0 = sf.x * 0.125f + bv.x;
    float x1 = sf.y * 0.125f + bv.y;
    float a0 = fabsf(x0), a1 = fabsf(x1);
    float e0 = __expf(-2.f * a0), e1 = __expf(-2.f * a1);
    float t0 = __fdividef(1.f - e0, 1.f + e0);
    float t1 = __fdividef(1.f - e1, 1.f + e1);
    t0 = copysignf(t0, x0);
    t1 = copysignf(t1, x1);
    float p = t0 * wv.x + t1 * wv.y;
    #pragma unroll
    for (int off = 16; off; off >>= 1) p += __shfl_xor(p, off);
    if (fl == 0 && n < N) s1[(size_t)q * N + n] = p;
}

// ---------------- Stage 3 (fused): score + exp + Z-partial + weighted values ----------------
__global__ __launch_bounds__(256) void k_ctx(const float* __restrict__ values,
                                             const float* __restrict__ s1,
                                             const int* __restrict__ edges,
                                             const float* __restrict__ b2,
                                             float* __restrict__ score,
                                             float* __restrict__ partial,
                                             float* __restrict__ zpart, int N) {
    const int q = blockIdx.y, cb = blockIdx.x;
    const int tid = threadIdx.x;
    const int chunk = (N + CTXB - 1) / CTXB;     // 200
    const int n0 = cb * chunk, n1 = min(n0 + chunk, N);
    const int cnt = n1 - n0;
    __shared__ float wlds[256];
    __shared__ float zred[4];
    const float* s1q = s1 + (size_t)q * N;
    const float b2v = b2[0];

    // phase 1: scores + exp for this chunk (cnt = 200 <= 256)
    float zp = 0.f;
    if (tid < cnt) {
        int n = n0 + tid;
        float acc = 0.f;
        #pragma unroll
        for (int k = 0; k < KN; ++k) acc += s1q[edges[(size_t)n * KN + k]];
        float sc = acc * 0.125f + b2v;
        score[(size_t)q * N + n] = sc;
        float ex = __expf(sc);
        wlds[tid] = ex;
        zp = ex;
    }
    float z = zp;
    #pragma unroll
    for (int off = 32; off; off >>= 1) z += __shfl_xor(z, off);
    if ((tid & 63) == 0) zred[tid >> 6] = z;
    __syncthreads();

    // phase 2: weighted values stream (unroll-8, independent loads)
    const int fi = tid & 31, g = tid >> 5;
    const float4* v = (const float4*)(values + (size_t)q * N * FIN);
    float4 acc = make_float4(0.f, 0.f, 0.f, 0.f);
    int n = n0 + g;
    for (; n + 56 < n1; n += 64) {
        int l = n - n0;
        float w0 = wlds[l],      w1 = wlds[l + 8],  w2 = wlds[l + 16], w3 = wlds[l + 24];
        float w4 = wlds[l + 32], w5 = wlds[l + 40], w6 = wlds[l + 48], w7 = wlds[l + 56];
        float4 v0 = v[(size_t)n * 32 + fi];
        float4 v1 = v[(size_t)(n + 8) * 32 + fi];
        float4 v2 = v[(size_t)(n + 16) * 32 + fi];
        float4 v3 = v[(size_t)(n + 24) * 32 + fi];
        float4 v4 = v[(size_t)(n + 32) * 32 + fi];
        float4 v5 = v[(size_t)(n + 40) * 32 + fi];
        float4 v6 = v[(size_t)(n + 48) * 32 + fi];
        float4 v7 = v[(size_t)(n + 56) * 32 + fi];
        acc.x = fmaf(w0, v0.x, acc.x); acc.y = fmaf(w0, v0.y, acc.y);
        acc.z = fmaf(w0, v0.z, acc.z); acc.w = fmaf(w0, v0.w, acc.w);
        acc.x = fmaf(w1, v1.x, acc.x); acc.y = fmaf(w1, v1.y, acc.y);
        acc.z = fmaf(w1, v1.z, acc.z); acc.w = fmaf(w1, v1.w, acc.w);
        acc.x = fmaf(w2, v2.x, acc.x); acc.y = fmaf(w2, v2.y, acc.y);
        acc.z = fmaf(w2, v2.z, acc.z); acc.w = fmaf(w2, v2.w, acc.w);
        acc.x = fmaf(w3, v3.x, acc.x); acc.y = fmaf(w3, v3.y, acc.y);
        acc.z = fmaf(w3, v3.z, acc.z); acc.w = fmaf(w3, v3.w, acc.w);
        acc.x = fmaf(w4, v4.x, acc.x); acc.y = fmaf(w4, v4.y, acc.y);
        acc.z = fmaf(w4, v4.z, acc.z); acc.w = fmaf(w4, v4.w, acc.w);
        acc.x = fmaf(w5, v5.x, acc.x); acc.y = fmaf(w5, v5.y, acc.y);
        acc.z = fmaf(w5, v5.z, acc.z); acc.w = fmaf(w5, v5.w, acc.w);
        acc.x = fmaf(w6, v6.x, acc.x); acc.y = fmaf(w6, v6.y, acc.y);
        acc.z = fmaf(w6, v6.z, acc.z); acc.w = fmaf(w6, v6.w, acc.w);
        acc.x = fmaf(w7, v7.x, acc.x); acc.y = fmaf(w7, v7.y, acc.y);
        acc.z = fmaf(w7, v7.z, acc.z); acc.w = fmaf(w7, v7.w, acc.w);
    }
    for (; n < n1; n += 8) {
        float ww = wlds[n - n0];
        float4 a = v[(size_t)n * 32 + fi];
        acc.x = fmaf(ww, a.x, acc.x);
        acc.y = fmaf(ww, a.y, acc.y);
        acc.z = fmaf(ww, a.z, acc.z);
        acc.w = fmaf(ww, a.w, acc.w);
    }
    __shared__ float4 part[256];
    part[tid] = acc;
    __syncthreads();
    if (tid < 32) {
        float4 a = part[tid];
        #pragma unroll
        for (int gg = 1; gg < 8; ++gg) {
            float4 b = part[gg * 32 + tid];
            a.x += b.x; a.y += b.y; a.z += b.z; a.w += b.w;
        }
        ((float4*)partial)[((size_t)q * CTXB + cb) * 32 + fi] = a;
    }
    if (tid == 0) zpart[(size_t)q * CTXB + cb] = zred[0] + zred[1] + zred[2] + zred[3];
}

// ---------------- Stage 4: ctx[q,f] = (Σ_cb partial[q,cb,f]) / (Σ_cb zpart[q,cb]) ----------------
__global__ __launch_bounds__(512) void k_final(const float* __restrict__ partial,
                                               const float* __restrict__ zpart,
                                               float* __restrict__ ctx) {
    const int q = blockIdx.x;
    const int tid = threadIdx.x;
    const int f = tid & 127, h = tid >> 7;
    const float* p = partial + (size_t)q * CTXB * FIN;
    float s = 0.f;
    for (int b = h; b < CTXB; b += 4) s += p[(size_t)b * FIN + f];
    __shared__ float red[512];
    __shared__ float zred[8];
    red[tid] = s;
    float z = (tid < CTXB) ? zpart[(size_t)q * CTXB + tid] : 0.f;
    #pragma unroll
    for (int off = 32; off; off >>= 1) z += __shfl_xor(z, off);
    if ((tid & 63) == 0) zred[tid >> 6] = z;
    __syncthreads();
    if (tid < 128) {
        float Zt = zred[0] + zred[1] + zred[2] + zred[3] +
                   zred[4] + zred[5] + zred[6] + zred[7];
        float t = red[tid] + red[tid + 128] + red[tid + 256] + red[tid + 384];
        ctx[q * FIN + f] = t * (1.f / Zt);
    }
}

extern "C" void kernel_launch(void* const* d_in, const int* in_sizes, int n_in,
                              void* d_out, int out_size, void* d_ws, size_t ws_size,
                              hipStream_t stream) {
    const float* query  = (const float*)d_in[0];
    const float* values = (const float*)d_in[1];
    const int*   edges  = (const int*)d_in[2];
    const float* W1     = (const float*)d_in[3];
    const float* b1     = (const float*)d_in[4];
    const float* W2     = (const float*)d_in[5];
    const float* b2     = (const float*)d_in[6];

    const int N = in_sizes[2] / KN;           // 50000
    const int Q = in_sizes[0] / (N * FIN);    // 4

    float* out   = (float*)d_out;
    float* ctx   = out;                       // [Q,128]
    float* score = out + (size_t)Q * FIN;     // [Q,N]

    char* ws = (char*)d_ws;
    __half* y = (__half*)ws;                                    // [Q,N,64] f16
    size_t off = (size_t)Q * N * FOUT * sizeof(__half);
    float* s1    = (float*)(ws + off);  off += (size_t)Q * N * sizeof(float);
    float* part  = (float*)(ws + off);  off += (size_t)Q * CTXB * FIN * sizeof(float);
    float* zpart = (float*)(ws + off);  off += (size_t)Q * CTXB * sizeof(float);
    short* W1pk  = (short*)(ws + off);                          // [2][1024][8]

    k_prep<<<16, 64, 0, stream>>>(W1, W1pk);
    dim3 g1((N + 127) / 128, Q);
    k_xw<<<g1, 256, 0, stream>>>(query, W1pk, y, N);
    dim3 g2((N + 7) / 8, Q);
    k_agg<<<g2, 256, 0, stream>>>(y, edges, b1, W2, s1, N);
    dim3 g3(CTXB, Q);
    k_ctx<<<g3, 256, 0, stream>>>(values, s1, edges, b2, score, part, zpart, N);
    k_final<<<Q, 512, 0, stream>>>(part, zpart, ctx);
}

// Round 11
// 87.672 us; speedup vs baseline: 1.1168x; 1.1168x over previous
//
#include <hip/hip_runtime.h>
#include <hip/hip_fp16.h>
#include <math.h>

// GraphAttention: Q=4, N=50000, K=8, F_IN=128, F_OUT=64
//   y  = query @ W1        (single-pass f16 MFMA; f16 out)
//   s1 = tanh(mean_k y[e]+b1) . W2
//   score = mean_k s1[e] + b2
//   softmax without max-sub (scores bounded ~|2|): w=exp(s)/Z
//   ctx = (sum_n exp(s_n) * values[n]) / Z
// 4 launches: k_xw (in-block f16 W1 pack -> LDS), k_agg (2 chains/wave),
// k_ctx (score+exp+weighted sum fused), k_final.

#define FIN 128
#define FOUT 64
#define KN 8
#define CTXB 250   // context blocks per q -> chunk = exactly 200 nodes

typedef _Float16 f16x8 __attribute__((ext_vector_type(8)));
typedef float f32x4 __attribute__((ext_vector_type(4)));

// ---------------- Stage 1: y = query @ W1 (f16 MFMA) ----------------
// In-block pack: 1024 fragment rows, each thread builds 4 rows (8 scalar
// L2-hot W1 reads + 8 cvt each), conflict-free ds_write_b128. 16 KB LDS.
__global__ __launch_bounds__(256, 3) void k_xw(const float* __restrict__ query,
                                               const float* __restrict__ W1,
                                               __half* __restrict__ y, int N) {
    __shared__ _Float16 Wlds[8192];   // [16 frags][64 lanes][8 f16]
    const int tid = threadIdx.x;
    #pragma unroll
    for (int it = 0; it < 4; ++it) {
        int p = it * 256 + tid;        // fragment-row index 0..1023
        int g6 = p >> 6;               // kk*4 + nt  (0..15)
        int kk = g6 >> 2, nt = g6 & 3;
        int lane6 = p & 63;
        int lg = lane6 >> 4, lr = lane6 & 15;
        int f = nt * 16 + lr;
        int kbase = kk * 32 + lg * 8;
        f16x8 fr;
        #pragma unroll
        for (int j = 0; j < 8; ++j)
            fr[j] = (_Float16)W1[(kbase + j) * FOUT + f];
        ((f16x8*)Wlds)[p] = fr;
    }
    __syncthreads();

    const int wave = tid >> 6, lane = tid & 63;
    const int lg = lane >> 4, lr = lane & 15;
    const int q = blockIdx.y;
    const int base = blockIdx.x * 128 + wave * 32;
    const float* qb = query + (size_t)q * N * FIN;
    __half* yq = y + (size_t)q * N * FOUT;
    const f16x8* Bp = (const f16x8*)Wlds;

    int n0 = base + lr;       if (n0 >= N) n0 = N - 1;
    int n1 = base + 16 + lr;  if (n1 >= N) n1 = N - 1;
    const float4* r0 = (const float4*)(qb + (size_t)n0 * FIN);
    const float4* r1 = (const float4*)(qb + (size_t)n1 * FIN);

    float4 a0[8], a1[8];
    #pragma unroll
    for (int kk = 0; kk < 4; ++kk) {
        a0[2 * kk]     = r0[kk * 8 + lg * 2];
        a0[2 * kk + 1] = r0[kk * 8 + lg * 2 + 1];
        a1[2 * kk]     = r1[kk * 8 + lg * 2];
        a1[2 * kk + 1] = r1[kk * 8 + lg * 2 + 1];
    }

    f32x4 acc0[4], acc1[4];
    #pragma unroll
    for (int nt = 0; nt < 4; ++nt) { acc0[nt] = (f32x4)0.f; acc1[nt] = (f32x4)0.f; }

    #pragma unroll
    for (int kk = 0; kk < 4; ++kk) {
        f16x8 A0, A1;
        const float* x0 = (const float*)&a0[2 * kk];
        const float* x1 = (const float*)&a1[2 * kk];
        #pragma unroll
        for (int j = 0; j < 8; ++j) { A0[j] = (_Float16)x0[j]; A1[j] = (_Float16)x1[j]; }
        #pragma unroll
        for (int nt = 0; nt < 4; ++nt) {
            f16x8 Bf = Bp[(kk * 4 + nt) * 64 + lane];
            acc0[nt] = __builtin_amdgcn_mfma_f32_16x16x32_f16(A0, Bf, acc0[nt], 0, 0, 0);
            acc1[nt] = __builtin_amdgcn_mfma_f32_16x16x32_f16(A1, Bf, acc1[nt], 0, 0, 0);
        }
    }
    #pragma unroll
    for (int r = 0; r < 4; ++r) {
        int m0 = base + lg * 4 + r;
        int m1 = base + 16 + lg * 4 + r;
        if (m0 < N) {
            #pragma unroll
            for (int nt = 0; nt < 4; ++nt)
                yq[(size_t)m0 * FOUT + nt * 16 + lr] = __float2half(acc0[nt][r]);
        }
        if (m1 < N) {
            #pragma unroll
            for (int nt = 0; nt < 4; ++nt)
                yq[(size_t)m1 * FOUT + nt * 16 + lr] = __float2half(acc1[nt][r]);
        }
    }
}

// ---------------- Stage 2: s1 = tanh(mean_k y[e]+b1).W2 ----------------
// 2 node-chains per wave (nodes nA, nA+8), 16 independent gathers in flight.
__global__ __launch_bounds__(256) void k_agg(const __half* __restrict__ y,
                                             const int* __restrict__ edges,
                                             const float* __restrict__ b1,
                                             const float* __restrict__ W2,
                                             float* __restrict__ s1, int N) {
    const int tid = threadIdx.x;
    const int wave = tid >> 6, lane = tid & 63;
    const int half = lane >> 5, fl = lane & 31;
    const int q = blockIdx.y;
    const int nA = blockIdx.x * 16 + wave * 2 + half;
    const int nB = nA + 8;
    const int ncA = nA < N ? nA : N - 1;
    const int ncB = nB < N ? nB : N - 1;
    const __half2* y2 = (const __half2*)(y + (size_t)q * N * FOUT);

    const int4* erA = (const int4*)(edges + (size_t)ncA * KN);
    const int4* erB = (const int4*)(edges + (size_t)ncB * KN);
    int4 eaA = erA[0], ebA = erA[1];
    int4 eaB = erB[0], ebB = erB[1];

    __half2 a0 = y2[(size_t)eaA.x * 32 + fl], a1 = y2[(size_t)eaA.y * 32 + fl];
    __half2 a2 = y2[(size_t)eaA.z * 32 + fl], a3 = y2[(size_t)eaA.w * 32 + fl];
    __half2 a4 = y2[(size_t)ebA.x * 32 + fl], a5 = y2[(size_t)ebA.y * 32 + fl];
    __half2 a6 = y2[(size_t)ebA.z * 32 + fl], a7 = y2[(size_t)ebA.w * 32 + fl];
    __half2 c0 = y2[(size_t)eaB.x * 32 + fl], c1 = y2[(size_t)eaB.y * 32 + fl];
    __half2 c2 = y2[(size_t)eaB.z * 32 + fl], c3 = y2[(size_t)eaB.w * 32 + fl];
    __half2 c4 = y2[(size_t)ebB.x * 32 + fl], c5 = y2[(size_t)ebB.y * 32 + fl];
    __half2 c6 = y2[(size_t)ebB.z * 32 + fl], c7 = y2[(size_t)ebB.w * 32 + fl];

    __half2 sA = __hadd2(__hadd2(__hadd2(a0, a1), __hadd2(a2, a3)),
                         __hadd2(__hadd2(a4, a5), __hadd2(a6, a7)));
    __half2 sB = __hadd2(__hadd2(__hadd2(c0, c1), __hadd2(c2, c3)),
                         __hadd2(__hadd2(c4, c5), __hadd2(c6, c7)));
    float2 fA = __half22float2(sA);
    float2 fB = __half22float2(sB);

    float2 bv = *(const float2*)(b1 + fl * 2);
    float2 wv = *(const float2*)(W2 + fl * 2);

    float xA0 = fA.x * 0.125f + bv.x, xA1 = fA.y * 0.125f + bv.y;
    float xB0 = fB.x * 0.125f + bv.x, xB1 = fB.y * 0.125f + bv.y;
    float eA0 = __expf(-2.f * fabsf(xA0)), eA1 = __expf(-2.f * fabsf(xA1));
    float eB0 = __expf(-2.f * fabsf(xB0)), eB1 = __expf(-2.f * fabsf(xB1));
    float tA0 = copysignf(__fdividef(1.f - eA0, 1.f + eA0), xA0);
    float tA1 = copysignf(__fdividef(1.f - eA1, 1.f + eA1), xA1);
    float tB0 = copysignf(__fdividef(1.f - eB0, 1.f + eB0), xB0);
    float tB1 = copysignf(__fdividef(1.f - eB1, 1.f + eB1), xB1);
    float pA = tA0 * wv.x + tA1 * wv.y;
    float pB = tB0 * wv.x + tB1 * wv.y;
    #pragma unroll
    for (int off = 16; off; off >>= 1) {
        pA += __shfl_xor(pA, off);
        pB += __shfl_xor(pB, off);
    }
    if (fl == 0) {
        float* s1q = s1 + (size_t)q * N;
        if (nA < N) s1q[nA] = pA;
        if (nB < N) s1q[nB] = pB;
    }
}

// ---------------- Stage 3 (fused): score + exp + Z-partial + weighted values ----------------
__global__ __launch_bounds__(256) void k_ctx(const float* __restrict__ values,
                                             const float* __restrict__ s1,
                                             const int* __restrict__ edges,
                                             const float* __restrict__ b2,
                                             float* __restrict__ score,
                                             float* __restrict__ partial,
                                             float* __restrict__ zpart, int N) {
    const int q = blockIdx.y, cb = blockIdx.x;
    const int tid = threadIdx.x;
    const int chunk = (N + CTXB - 1) / CTXB;     // 200
    const int n0 = cb * chunk, n1 = min(n0 + chunk, N);
    const int cnt = n1 - n0;
    __shared__ float wlds[256];
    __shared__ float zred[4];
    const float* s1q = s1 + (size_t)q * N;
    const float b2v = b2[0];

    float zp = 0.f;
    if (tid < cnt) {
        int n = n0 + tid;
        float acc = 0.f;
        #pragma unroll
        for (int k = 0; k < KN; ++k) acc += s1q[edges[(size_t)n * KN + k]];
        float sc = acc * 0.125f + b2v;
        score[(size_t)q * N + n] = sc;
        float ex = __expf(sc);
        wlds[tid] = ex;
        zp = ex;
    }
    float z = zp;
    #pragma unroll
    for (int off = 32; off; off >>= 1) z += __shfl_xor(z, off);
    if ((tid & 63) == 0) zred[tid >> 6] = z;
    __syncthreads();

    const int fi = tid & 31, g = tid >> 5;
    const float4* v = (const float4*)(values + (size_t)q * N * FIN);
    float4 acc = make_float4(0.f, 0.f, 0.f, 0.f);
    int n = n0 + g;
    for (; n + 56 < n1; n += 64) {
        int l = n - n0;
        float w0 = wlds[l],      w1 = wlds[l + 8],  w2 = wlds[l + 16], w3 = wlds[l + 24];
        float w4 = wlds[l + 32], w5 = wlds[l + 40], w6 = wlds[l + 48], w7 = wlds[l + 56];
        float4 v0 = v[(size_t)n * 32 + fi];
        float4 v1 = v[(size_t)(n + 8) * 32 + fi];
        float4 v2 = v[(size_t)(n + 16) * 32 + fi];
        float4 v3 = v[(size_t)(n + 24) * 32 + fi];
        float4 v4 = v[(size_t)(n + 32) * 32 + fi];
        float4 v5 = v[(size_t)(n + 40) * 32 + fi];
        float4 v6 = v[(size_t)(n + 48) * 32 + fi];
        float4 v7 = v[(size_t)(n + 56) * 32 + fi];
        acc.x = fmaf(w0, v0.x, acc.x); acc.y = fmaf(w0, v0.y, acc.y);
        acc.z = fmaf(w0, v0.z, acc.z); acc.w = fmaf(w0, v0.w, acc.w);
        acc.x = fmaf(w1, v1.x, acc.x); acc.y = fmaf(w1, v1.y, acc.y);
        acc.z = fmaf(w1, v1.z, acc.z); acc.w = fmaf(w1, v1.w, acc.w);
        acc.x = fmaf(w2, v2.x, acc.x); acc.y = fmaf(w2, v2.y, acc.y);
        acc.z = fmaf(w2, v2.z, acc.z); acc.w = fmaf(w2, v2.w, acc.w);
        acc.x = fmaf(w3, v3.x, acc.x); acc.y = fmaf(w3, v3.y, acc.y);
        acc.z = fmaf(w3, v3.z, acc.z); acc.w = fmaf(w3, v3.w, acc.w);
        acc.x = fmaf(w4, v4.x, acc.x); acc.y = fmaf(w4, v4.y, acc.y);
        acc.z = fmaf(w4, v4.z, acc.z); acc.w = fmaf(w4, v4.w, acc.w);
        acc.x = fmaf(w5, v5.x, acc.x); acc.y = fmaf(w5, v5.y, acc.y);
        acc.z = fmaf(w5, v5.z, acc.z); acc.w = fmaf(w5, v5.w, acc.w);
        acc.x = fmaf(w6, v6.x, acc.x); acc.y = fmaf(w6, v6.y, acc.y);
        acc.z = fmaf(w6, v6.z, acc.z); acc.w = fmaf(w6, v6.w, acc.w);
        acc.x = fmaf(w7, v7.x, acc.x); acc.y = fmaf(w7, v7.y, acc.y);
        acc.z = fmaf(w7, v7.z, acc.z); acc.w = fmaf(w7, v7.w, acc.w);
    }
    for (; n < n1; n += 8) {
        float ww = wlds[n - n0];
        float4 a = v[(size_t)n * 32 + fi];
        acc.x = fmaf(ww, a.x, acc.x);
        acc.y = fmaf(ww, a.y, acc.y);
        acc.z = fmaf(ww, a.z, acc.z);
        acc.w = fmaf(ww, a.w, acc.w);
    }
    __shared__ float4 part[256];
    part[tid] = acc;
    __syncthreads();
    if (tid < 32) {
        float4 a = part[tid];
        #pragma unroll
        for (int gg = 1; gg < 8; ++gg) {
            float4 b = part[gg * 32 + tid];
            a.x += b.x; a.y += b.y; a.z += b.z; a.w += b.w;
        }
        ((float4*)partial)[((size_t)q * CTXB + cb) * 32 + fi] = a;
    }
    if (tid == 0) zpart[(size_t)q * CTXB + cb] = zred[0] + zred[1] + zred[2] + zred[3];
}

// ---------------- Stage 4: ctx[q,f] = (Σ_cb partial[q,cb,f]) / (Σ_cb zpart[q,cb]) ----------------
__global__ __launch_bounds__(512) void k_final(const float* __restrict__ partial,
                                               const float* __restrict__ zpart,
                                               float* __restrict__ ctx) {
    const int q = blockIdx.x;
    const int tid = threadIdx.x;
    const int f = tid & 127, h = tid >> 7;
    const float* p = partial + (size_t)q * CTXB * FIN;
    float s = 0.f;
    for (int b = h; b < CTXB; b += 4) s += p[(size_t)b * FIN + f];
    __shared__ float red[512];
    __shared__ float zred[8];
    red[tid] = s;
    float z = (tid < CTXB) ? zpart[(size_t)q * CTXB + tid] : 0.f;
    #pragma unroll
    for (int off = 32; off; off >>= 1) z += __shfl_xor(z, off);
    if ((tid & 63) == 0) zred[tid >> 6] = z;
    __syncthreads();
    if (tid < 128) {
        float Zt = zred[0] + zred[1] + zred[2] + zred[3] +
                   zred[4] + zred[5] + zred[6] + zred[7];
        float t = red[tid] + red[tid + 128] + red[tid + 256] + red[tid + 384];
        ctx[q * FIN + f] = t * (1.f / Zt);
    }
}

extern "C" void kernel_launch(void* const* d_in, const int* in_sizes, int n_in,
                              void* d_out, int out_size, void* d_ws, size_t ws_size,
                              hipStream_t stream) {
    const float* query  = (const float*)d_in[0];
    const float* values = (const float*)d_in[1];
    const int*   edges  = (const int*)d_in[2];
    const float* W1     = (const float*)d_in[3];
    const float* b1     = (const float*)d_in[4];
    const float* W2     = (const float*)d_in[5];
    const float* b2     = (const float*)d_in[6];

    const int N = in_sizes[2] / KN;           // 50000
    const int Q = in_sizes[0] / (N * FIN);    // 4

    float* out   = (float*)d_out;
    float* ctx   = out;                       // [Q,128]
    float* score = out + (size_t)Q * FIN;     // [Q,N]

    char* ws = (char*)d_ws;
    __half* y = (__half*)ws;                                    // [Q,N,64] f16
    size_t off = (size_t)Q * N * FOUT * sizeof(__half);
    float* s1    = (float*)(ws + off);  off += (size_t)Q * N * sizeof(float);
    float* part  = (float*)(ws + off);  off += (size_t)Q * CTXB * FIN * sizeof(float);
    float* zpart = (float*)(ws + off);                          // [Q,CTXB]

    dim3 g1((N + 127) / 128, Q);
    k_xw<<<g1, 256, 0, stream>>>(query, W1, y, N);
    dim3 g2((N + 15) / 16, Q);
    k_agg<<<g2, 256, 0, stream>>>(y, edges, b1, W2, s1, N);
    dim3 g3(CTXB, Q);
    k_ctx<<<g3, 256, 0, stream>>>(values, s1, edges, b2, score, part, zpart, N);
    k_final<<<Q, 512, 0, stream>>>(part, zpart, ctx);
}

// Round 12
// 87.472 us; speedup vs baseline: 1.1194x; 1.0023x over previous
//
#include <hip/hip_runtime.h>
#include <hip/hip_fp16.h>
#include <math.h>

// GraphAttention: Q=4, N=50000, K=8, F_IN=128, F_OUT=64
//   y  = query @ W1        (single-pass f16 MFMA; f16 out)
//   s1 = tanh(mean_k y[e]+b1) . W2
//   score = mean_k s1[e] + b2
//   softmax without max-sub (scores bounded ~|2|): w=exp(s)/Z
//   ctx = (sum_n exp(s_n) * values[n]) / Z
// 4 launches. This round: explicit min-waves occupancy hints on k_agg/k_ctx
// so the compiler keeps the independent gathers/streams in flight (R2/R3
// precedent: default allocation reg-starves and serializes loads).

#define FIN 128
#define FOUT 64
#define KN 8
#define CTXB 250   // context blocks per q -> chunk = exactly 200 nodes

typedef _Float16 f16x8 __attribute__((ext_vector_type(8)));
typedef float f32x4 __attribute__((ext_vector_type(4)));

// ---------------- Stage 1: y = query @ W1 (f16 MFMA) ----------------
__global__ __launch_bounds__(256, 3) void k_xw(const float* __restrict__ query,
                                               const float* __restrict__ W1,
                                               __half* __restrict__ y, int N) {
    __shared__ _Float16 Wlds[8192];   // [16 frags][64 lanes][8 f16]
    const int tid = threadIdx.x;
    #pragma unroll
    for (int it = 0; it < 4; ++it) {
        int p = it * 256 + tid;        // fragment-row index 0..1023
        int g6 = p >> 6;               // kk*4 + nt  (0..15)
        int kk = g6 >> 2, nt = g6 & 3;
        int lane6 = p & 63;
        int lg = lane6 >> 4, lr = lane6 & 15;
        int f = nt * 16 + lr;
        int kbase = kk * 32 + lg * 8;
        f16x8 fr;
        #pragma unroll
        for (int j = 0; j < 8; ++j)
            fr[j] = (_Float16)W1[(kbase + j) * FOUT + f];
        ((f16x8*)Wlds)[p] = fr;
    }
    __syncthreads();

    const int wave = tid >> 6, lane = tid & 63;
    const int lg = lane >> 4, lr = lane & 15;
    const int q = blockIdx.y;
    const int base = blockIdx.x * 128 + wave * 32;
    const float* qb = query + (size_t)q * N * FIN;
    __half* yq = y + (size_t)q * N * FOUT;
    const f16x8* Bp = (const f16x8*)Wlds;

    int n0 = base + lr;       if (n0 >= N) n0 = N - 1;
    int n1 = base + 16 + lr;  if (n1 >= N) n1 = N - 1;
    const float4* r0 = (const float4*)(qb + (size_t)n0 * FIN);
    const float4* r1 = (const float4*)(qb + (size_t)n1 * FIN);

    float4 a0[8], a1[8];
    #pragma unroll
    for (int kk = 0; kk < 4; ++kk) {
        a0[2 * kk]     = r0[kk * 8 + lg * 2];
        a0[2 * kk + 1] = r0[kk * 8 + lg * 2 + 1];
        a1[2 * kk]     = r1[kk * 8 + lg * 2];
        a1[2 * kk + 1] = r1[kk * 8 + lg * 2 + 1];
    }

    f32x4 acc0[4], acc1[4];
    #pragma unroll
    for (int nt = 0; nt < 4; ++nt) { acc0[nt] = (f32x4)0.f; acc1[nt] = (f32x4)0.f; }

    #pragma unroll
    for (int kk = 0; kk < 4; ++kk) {
        f16x8 A0, A1;
        const float* x0 = (const float*)&a0[2 * kk];
        const float* x1 = (const float*)&a1[2 * kk];
        #pragma unroll
        for (int j = 0; j < 8; ++j) { A0[j] = (_Float16)x0[j]; A1[j] = (_Float16)x1[j]; }
        #pragma unroll
        for (int nt = 0; nt < 4; ++nt) {
            f16x8 Bf = Bp[(kk * 4 + nt) * 64 + lane];
            acc0[nt] = __builtin_amdgcn_mfma_f32_16x16x32_f16(A0, Bf, acc0[nt], 0, 0, 0);
            acc1[nt] = __builtin_amdgcn_mfma_f32_16x16x32_f16(A1, Bf, acc1[nt], 0, 0, 0);
        }
    }
    #pragma unroll
    for (int r = 0; r < 4; ++r) {
        int m0 = base + lg * 4 + r;
        int m1 = base + 16 + lg * 4 + r;
        if (m0 < N) {
            #pragma unroll
            for (int nt = 0; nt < 4; ++nt)
                yq[(size_t)m0 * FOUT + nt * 16 + lr] = __float2half(acc0[nt][r]);
        }
        if (m1 < N) {
            #pragma unroll
            for (int nt = 0; nt < 4; ++nt)
                yq[(size_t)m1 * FOUT + nt * 16 + lr] = __float2half(acc1[nt][r]);
        }
    }
}

// ---------------- Stage 2: s1 = tanh(mean_k y[e]+b1).W2 ----------------
// 2 node-chains per wave, 16 independent gathers in flight; min-4-waves
// occupancy hint so all 16 stay live (VGPR cap 128, not 32).
__global__ __launch_bounds__(256, 4) void k_agg(const __half* __restrict__ y,
                                                const int* __restrict__ edges,
                                                const float* __restrict__ b1,
                                                const float* __restrict__ W2,
                                                float* __restrict__ s1, int N) {
    const int tid = threadIdx.x;
    const int wave = tid >> 6, lane = tid & 63;
    const int half = lane >> 5, fl = lane & 31;
    const int q = blockIdx.y;
    const int nA = blockIdx.x * 16 + wave * 2 + half;
    const int nB = nA + 8;
    const int ncA = nA < N ? nA : N - 1;
    const int ncB = nB < N ? nB : N - 1;
    const __half2* y2 = (const __half2*)(y + (size_t)q * N * FOUT);

    const int4* erA = (const int4*)(edges + (size_t)ncA * KN);
    const int4* erB = (const int4*)(edges + (size_t)ncB * KN);
    int4 eaA = erA[0], ebA = erA[1];
    int4 eaB = erB[0], ebB = erB[1];

    __half2 a0 = y2[(size_t)eaA.x * 32 + fl], a1 = y2[(size_t)eaA.y * 32 + fl];
    __half2 a2 = y2[(size_t)eaA.z * 32 + fl], a3 = y2[(size_t)eaA.w * 32 + fl];
    __half2 a4 = y2[(size_t)ebA.x * 32 + fl], a5 = y2[(size_t)ebA.y * 32 + fl];
    __half2 a6 = y2[(size_t)ebA.z * 32 + fl], a7 = y2[(size_t)ebA.w * 32 + fl];
    __half2 c0 = y2[(size_t)eaB.x * 32 + fl], c1 = y2[(size_t)eaB.y * 32 + fl];
    __half2 c2 = y2[(size_t)eaB.z * 32 + fl], c3 = y2[(size_t)eaB.w * 32 + fl];
    __half2 c4 = y2[(size_t)ebB.x * 32 + fl], c5 = y2[(size_t)ebB.y * 32 + fl];
    __half2 c6 = y2[(size_t)ebB.z * 32 + fl], c7 = y2[(size_t)ebB.w * 32 + fl];

    __half2 sA = __hadd2(__hadd2(__hadd2(a0, a1), __hadd2(a2, a3)),
                         __hadd2(__hadd2(a4, a5), __hadd2(a6, a7)));
    __half2 sB = __hadd2(__hadd2(__hadd2(c0, c1), __hadd2(c2, c3)),
                         __hadd2(__hadd2(c4, c5), __hadd2(c6, c7)));
    float2 fA = __half22float2(sA);
    float2 fB = __half22float2(sB);

    float2 bv = *(const float2*)(b1 + fl * 2);
    float2 wv = *(const float2*)(W2 + fl * 2);

    float xA0 = fA.x * 0.125f + bv.x, xA1 = fA.y * 0.125f + bv.y;
    float xB0 = fB.x * 0.125f + bv.x, xB1 = fB.y * 0.125f + bv.y;
    float eA0 = __expf(-2.f * fabsf(xA0)), eA1 = __expf(-2.f * fabsf(xA1));
    float eB0 = __expf(-2.f * fabsf(xB0)), eB1 = __expf(-2.f * fabsf(xB1));
    float tA0 = copysignf(__fdividef(1.f - eA0, 1.f + eA0), xA0);
    float tA1 = copysignf(__fdividef(1.f - eA1, 1.f + eA1), xA1);
    float tB0 = copysignf(__fdividef(1.f - eB0, 1.f + eB0), xB0);
    float tB1 = copysignf(__fdividef(1.f - eB1, 1.f + eB1), xB1);
    float pA = tA0 * wv.x + tA1 * wv.y;
    float pB = tB0 * wv.x + tB1 * wv.y;
    #pragma unroll
    for (int off = 16; off; off >>= 1) {
        pA += __shfl_xor(pA, off);
        pB += __shfl_xor(pB, off);
    }
    if (fl == 0) {
        float* s1q = s1 + (size_t)q * N;
        if (nA < N) s1q[nA] = pA;
        if (nB < N) s1q[nB] = pB;
    }
}

// ---------------- Stage 3 (fused): score + exp + Z-partial + weighted values ----------------
__global__ __launch_bounds__(256, 4) void k_ctx(const float* __restrict__ values,
                                                const float* __restrict__ s1,
                                                const int* __restrict__ edges,
                                                const float* __restrict__ b2,
                                                float* __restrict__ score,
                                                float* __restrict__ partial,
                                                float* __restrict__ zpart, int N) {
    const int q = blockIdx.y, cb = blockIdx.x;
    const int tid = threadIdx.x;
    const int chunk = (N + CTXB - 1) / CTXB;     // 200
    const int n0 = cb * chunk, n1 = min(n0 + chunk, N);
    const int cnt = n1 - n0;
    __shared__ float wlds[256];
    __shared__ float zred[4];
    const float* s1q = s1 + (size_t)q * N;
    const float b2v = b2[0];

    float zp = 0.f;
    if (tid < cnt) {
        int n = n0 + tid;
        float acc = 0.f;
        #pragma unroll
        for (int k = 0; k < KN; ++k) acc += s1q[edges[(size_t)n * KN + k]];
        float sc = acc * 0.125f + b2v;
        score[(size_t)q * N + n] = sc;
        float ex = __expf(sc);
        wlds[tid] = ex;
        zp = ex;
    }
    float z = zp;
    #pragma unroll
    for (int off = 32; off; off >>= 1) z += __shfl_xor(z, off);
    if ((tid & 63) == 0) zred[tid >> 6] = z;
    __syncthreads();

    const int fi = tid & 31, g = tid >> 5;
    const float4* v = (const float4*)(values + (size_t)q * N * FIN);
    float4 acc = make_float4(0.f, 0.f, 0.f, 0.f);
    int n = n0 + g;
    for (; n + 56 < n1; n += 64) {
        int l = n - n0;
        float w0 = wlds[l],      w1 = wlds[l + 8],  w2 = wlds[l + 16], w3 = wlds[l + 24];
        float w4 = wlds[l + 32], w5 = wlds[l + 40], w6 = wlds[l + 48], w7 = wlds[l + 56];
        float4 v0 = v[(size_t)n * 32 + fi];
        float4 v1 = v[(size_t)(n + 8) * 32 + fi];
        float4 v2 = v[(size_t)(n + 16) * 32 + fi];
        float4 v3 = v[(size_t)(n + 24) * 32 + fi];
        float4 v4 = v[(size_t)(n + 32) * 32 + fi];
        float4 v5 = v[(size_t)(n + 40) * 32 + fi];
        float4 v6 = v[(size_t)(n + 48) * 32 + fi];
        float4 v7 = v[(size_t)(n + 56) * 32 + fi];
        acc.x = fmaf(w0, v0.x, acc.x); acc.y = fmaf(w0, v0.y, acc.y);
        acc.z = fmaf(w0, v0.z, acc.z); acc.w = fmaf(w0, v0.w, acc.w);
        acc.x = fmaf(w1, v1.x, acc.x); acc.y = fmaf(w1, v1.y, acc.y);
        acc.z = fmaf(w1, v1.z, acc.z); acc.w = fmaf(w1, v1.w, acc.w);
        acc.x = fmaf(w2, v2.x, acc.x); acc.y = fmaf(w2, v2.y, acc.y);
        acc.z = fmaf(w2, v2.z, acc.z); acc.w = fmaf(w2, v2.w, acc.w);
        acc.x = fmaf(w3, v3.x, acc.x); acc.y = fmaf(w3, v3.y, acc.y);
        acc.z = fmaf(w3, v3.z, acc.z); acc.w = fmaf(w3, v3.w, acc.w);
        acc.x = fmaf(w4, v4.x, acc.x); acc.y = fmaf(w4, v4.y, acc.y);
        acc.z = fmaf(w4, v4.z, acc.z); acc.w = fmaf(w4, v4.w, acc.w);
        acc.x = fmaf(w5, v5.x, acc.x); acc.y = fmaf(w5, v5.y, acc.y);
        acc.z = fmaf(w5, v5.z, acc.z); acc.w = fmaf(w5, v5.w, acc.w);
        acc.x = fmaf(w6, v6.x, acc.x); acc.y = fmaf(w6, v6.y, acc.y);
        acc.z = fmaf(w6, v6.z, acc.z); acc.w = fmaf(w6, v6.w, acc.w);
        acc.x = fmaf(w7, v7.x, acc.x); acc.y = fmaf(w7, v7.y, acc.y);
        acc.z = fmaf(w7, v7.z, acc.z); acc.w = fmaf(w7, v7.w, acc.w);
    }
    for (; n < n1; n += 8) {
        float ww = wlds[n - n0];
        float4 a = v[(size_t)n * 32 + fi];
        acc.x = fmaf(ww, a.x, acc.x);
        acc.y = fmaf(ww, a.y, acc.y);
        acc.z = fmaf(ww, a.z, acc.z);
        acc.w = fmaf(ww, a.w, acc.w);
    }
    __shared__ float4 part[256];
    part[tid] = acc;
    __syncthreads();
    if (tid < 32) {
        float4 a = part[tid];
        #pragma unroll
        for (int gg = 1; gg < 8; ++gg) {
            float4 b = part[gg * 32 + tid];
            a.x += b.x; a.y += b.y; a.z += b.z; a.w += b.w;
        }
        ((float4*)partial)[((size_t)q * CTXB + cb) * 32 + fi] = a;
    }
    if (tid == 0) zpart[(size_t)q * CTXB + cb] = zred[0] + zred[1] + zred[2] + zred[3];
}

// ---------------- Stage 4: ctx[q,f] = (Σ_cb partial[q,cb,f]) / (Σ_cb zpart[q,cb]) ----------------
__global__ __launch_bounds__(512) void k_final(const float* __restrict__ partial,
                                               const float* __restrict__ zpart,
                                               float* __restrict__ ctx) {
    const int q = blockIdx.x;
    const int tid = threadIdx.x;
    const int f = tid & 127, h = tid >> 7;
    const float* p = partial + (size_t)q * CTXB * FIN;
    float s = 0.f;
    for (int b = h; b < CTXB; b += 4) s += p[(size_t)b * FIN + f];
    __shared__ float red[512];
    __shared__ float zred[8];
    red[tid] = s;
    float z = (tid < CTXB) ? zpart[(size_t)q * CTXB + tid] : 0.f;
    #pragma unroll
    for (int off = 32; off; off >>= 1) z += __shfl_xor(z, off);
    if ((tid & 63) == 0) zred[tid >> 6] = z;
    __syncthreads();
    if (tid < 128) {
        float Zt = zred[0] + zred[1] + zred[2] + zred[3] +
                   zred[4] + zred[5] + zred[6] + zred[7];
        float t = red[tid] + red[tid + 128] + red[tid + 256] + red[tid + 384];
        ctx[q * FIN + f] = t * (1.f / Zt);
    }
}

extern "C" void kernel_launch(void* const* d_in, const int* in_sizes, int n_in,
                              void* d_out, int out_size, void* d_ws, size_t ws_size,
                              hipStream_t stream) {
    const float* query  = (const float*)d_in[0];
    const float* values = (const float*)d_in[1];
    const int*   edges  = (const int*)d_in[2];
    const float* W1     = (const float*)d_in[3];
    const float* b1     = (const float*)d_in[4];
    const float* W2     = (const float*)d_in[5];
    const float* b2     = (const float*)d_in[6];

    const int N = in_sizes[2] / KN;           // 50000
    const int Q = in_sizes[0] / (N * FIN);    // 4

    float* out   = (float*)d_out;
    float* ctx   = out;                       // [Q,128]
    float* score = out + (size_t)Q * FIN;     // [Q,N]

    char* ws = (char*)d_ws;
    __half* y = (__half*)ws;                                    // [Q,N,64] f16
    size_t off = (size_t)Q * N * FOUT * sizeof(__half);
    float* s1    = (float*)(ws + off);  off += (size_t)Q * N * sizeof(float);
    float* part  = (float*)(ws + off);  off += (size_t)Q * CTXB * FIN * sizeof(float);
    float* zpart = (float*)(ws + off);                          // [Q,CTXB]

    dim3 g1((N + 127) / 128, Q);
    k_xw<<<g1, 256, 0, stream>>>(query, W1, y, N);
    dim3 g2((N + 15) / 16, Q);
    k_agg<<<g2, 256, 0, stream>>>(y, edges, b1, W2, s1, N);
    dim3 g3(CTXB, Q);
    k_ctx<<<g3, 256, 0, stream>>>(values, s1, edges, b2, score, part, zpart, N);
    k_final<<<Q, 512, 0, stream>>>(part, zpart, ctx);
}